// Round 10
// baseline (953.003 us; speedup 1.0000x reference)
//
#include <hip/hip_runtime.h>
#include <hip/hip_cooperative_groups.h>

namespace cg = cooperative_groups;

#define B_ 2
#define S_ 2048
#define D_ 1024
#define H_ 16
#define DK_ 64
#define M_ 4096   // B_*S_

typedef unsigned short u16;
typedef __bf16 bf16x8 __attribute__((ext_vector_type(8)));
typedef float floatx4 __attribute__((ext_vector_type(4)));

#if __has_builtin(__builtin_amdgcn_exp2f)
#define EXP2F(x) __builtin_amdgcn_exp2f(x)
#else
#define EXP2F(x) exp2f(x)
#endif

__device__ __forceinline__ u16 f2bf(float f) {
  unsigned u = __float_as_uint(f);
  u += 0x7fffu + ((u >> 16) & 1u);  // RNE
  return (u16)(u >> 16);
}

// async global->LDS, 16B/lane; l is the wave-uniform base, data lands at l+lane*16
__device__ __forceinline__ void stage16(const void* g, void* l) {
  __builtin_amdgcn_global_load_lds(
      (const __attribute__((address_space(1))) unsigned int*)g,
      (__attribute__((address_space(3))) unsigned int*)l, 16, 0, 0);
}

// ---------------- cvt phase: fp32 -> bf16, 16M elems over 1024 block-slots ---
__device__ __forceinline__ void cvt_phase(
    int bx, const float* q, const float* k, const float* v,
    const float* Wq, const float* Wk, const float* Wv, const float* Wo,
    u16* dq, u16* dk, u16* dv, u16* dwq, u16* dwk, u16* dwv, u16* dwo) {
  const float* s; u16* d; int slice;
  if (bx < 768) {
    const int t0 = bx >> 8;
    s = t0 == 0 ? q : t0 == 1 ? k : v;
    d = t0 == 0 ? dq : t0 == 1 ? dk : dv;
    slice = bx & 255;
  } else {
    const int t0 = (bx - 768) >> 6;
    s = t0 == 0 ? Wq : t0 == 1 ? Wk : t0 == 2 ? Wv : Wo;
    d = t0 == 0 ? dwq : t0 == 1 ? dwk : t0 == 2 ? dwv : dwo;
    slice = (bx - 768) & 63;
  }
  const size_t base = (size_t)slice * 16384 + (size_t)threadIdx.x * 8;
#pragma unroll
  for (int it = 0; it < 8; it++) {
    const size_t i = base + (size_t)it * 2048;
    const float4 f0 = *reinterpret_cast<const float4*>(s + i);
    const float4 f1 = *reinterpret_cast<const float4*>(s + i + 4);
    union { u16 h[8]; uint4 u; } cv;
    cv.h[0] = f2bf(f0.x); cv.h[1] = f2bf(f0.y); cv.h[2] = f2bf(f0.z); cv.h[3] = f2bf(f0.w);
    cv.h[4] = f2bf(f1.x); cv.h[5] = f2bf(f1.y); cv.h[6] = f2bf(f1.z); cv.h[7] = f2bf(f1.w);
    *reinterpret_cast<uint4*>(d + i) = cv.u;
  }
}

// ---------------- GEMM phase: C = A @ W^T + bias, bf16 in, BK=32 dbuf --------
// Register-light: BM=128/BN=64 -> acc[4][2]=32; BM=64/BN=64 -> acc[2][2]=16.
// Row-pair XOR swizzle (staging coalesced + b128 reads 2-way max).
// mode 0: bf16 heads [b,h,s,dk]*scale. mode 2: V^T [b,h,dk,s]. mode 3: fp32 [M,1024].
template <int BM, int BN>
__device__ __forceinline__ void gemm_phase(
    u16* smem, const u16* __restrict__ A, const u16* __restrict__ W,
    const float* __restrict__ bias, void* __restrict__ outp,
    int mode, float scale, int m0, int n0) {
  constexpr int MT = BM / 32;
  constexpr int NT = BN / 32;
  constexpr int NAI = BM / 64;
  constexpr int NBI = BN / 64;
  u16* As = smem;                  // [2][BM*32]
  u16* Bs = smem + 2 * BM * 32;    // [2][BN*32]

  const int t = threadIdx.x;
  const int lane = t & 63, w = t >> 6;
  const int quad = lane >> 4, l16 = lane & 15;
  const int wm = w >> 1, wn = w & 1;

  const int sp = lane >> 3, ssw = lane & 7, sc = ssw ^ sp;  // staging unswizzle
  const u16 *gA[NAI], *gB[NBI]; u16 *lA[NAI], *lB[NBI];
#pragma unroll
  for (int i = 0; i < NAI; i++) {
    const int ri = i * 4 + w;
    gA[i] = A + (size_t)(m0 + ri * 16 + 2 * sp + (sc >> 2)) * 1024 + (sc & 3) * 8;
    lA[i] = As + ri * 64 * 8;
  }
#pragma unroll
  for (int i = 0; i < NBI; i++) {
    const int ri = i * 4 + w;
    gB[i] = W + (size_t)(n0 + ri * 16 + 2 * sp + (sc >> 2)) * 1024 + (sc & 3) * 8;
    lB[i] = Bs + ri * 64 * 8;
  }

  floatx4 acc[MT][NT] = {};

#pragma unroll
  for (int i = 0; i < NAI; i++) stage16(gA[i], lA[i]);
#pragma unroll
  for (int i = 0; i < NBI; i++) stage16(gB[i], lB[i]);

  for (int k0 = 0; k0 < 1024; k0 += 32) {
    const int cur = (k0 >> 5) & 1, nxt = cur ^ 1;
    __syncthreads();
    if (k0 + 32 < 1024) {
#pragma unroll
      for (int i = 0; i < NAI; i++) stage16(gA[i] + k0 + 32, lA[i] + nxt * BM * 32);
#pragma unroll
      for (int i = 0; i < NBI; i++) stage16(gB[i] + k0 + 32, lB[i] + nxt * BN * 32);
    }
    bf16x8 af[MT], bf[NT];
#pragma unroll
    for (int mt = 0; mt < MT; mt++) {
      const int row = wm * (BM / 2) + mt * 16 + l16;
      const int pg = row >> 1;
      const int sw = (((row & 1) << 2) | quad) ^ (pg & 7);
      af[mt] = *reinterpret_cast<const bf16x8*>(&As[cur * BM * 32 + (pg * 8 + sw) * 8]);
    }
#pragma unroll
    for (int nt = 0; nt < NT; nt++) {
      const int row = wn * (BN / 2) + nt * 16 + l16;
      const int pg = row >> 1;
      const int sw = (((row & 1) << 2) | quad) ^ (pg & 7);
      bf[nt] = *reinterpret_cast<const bf16x8*>(&Bs[cur * BN * 32 + (pg * 8 + sw) * 8]);
    }
#pragma unroll
    for (int mt = 0; mt < MT; mt++)
#pragma unroll
      for (int nt = 0; nt < NT; nt++)
        acc[mt][nt] = __builtin_amdgcn_mfma_f32_16x16x32_bf16(af[mt], bf[nt], acc[mt][nt], 0, 0, 0);
  }

  // Epilogue. C row = quad*4+r, col = l16 (m89/m91 layout).
#pragma unroll
  for (int mt = 0; mt < MT; mt++) {
    const int mbase = m0 + wm * (BM / 2) + mt * 16 + quad * 4;
    const int bb = mbase >> 11, s0v = mbase & 2047;
#pragma unroll
    for (int nt = 0; nt < NT; nt++) {
      const int n = n0 + wn * (BN / 2) + nt * 16 + l16;
      const float bvv = bias[n];
      if (mode == 0) {
        u16* Y = (u16*)outp;
        const int h = n >> 6, dk = n & 63;
#pragma unroll
        for (int r = 0; r < 4; r++)
          Y[(((size_t)(bb * H_ + h)) * S_ + (s0v + r)) * DK_ + dk] =
              f2bf((acc[mt][nt][r] + bvv) * scale);
      } else if (mode == 2) {
        u16* Y = (u16*)outp;
        const int h = n >> 6, dk = n & 63;
        union { u16 h4[4]; uint2 u; } pk2;
#pragma unroll
        for (int r = 0; r < 4; r++) pk2.h4[r] = f2bf(acc[mt][nt][r] + bvv);
        *reinterpret_cast<uint2*>(
            &Y[(((size_t)(bb * H_ + h)) * DK_ + dk) * S_ + s0v]) = pk2.u;
      } else {  // mode 3: fp32 [M,1024]
        float* Y = (float*)outp;
#pragma unroll
        for (int r = 0; r < 4; r++)
          Y[(size_t)(mbase + r) * 1024 + n] = acc[mt][nt][r] + bvv;
      }
    }
  }
}

// QKV job j in [0,1536): g=j>>9 (0:Q 1:K 2:V), r=j&511, m0=(r&31)*128, n0=(r>>5)*64
__device__ __forceinline__ void qkv_job(
    u16* smem, int j, const u16* qb_, const u16* kb_, const u16* vb_,
    const u16* wqb, const u16* wkb, const u16* wvb,
    const float* bq, const float* bk, const float* bv,
    u16* Qh, u16* Kh, u16* VhT) {
  const int g = j >> 9, r = j & 511;
  const int m0 = (r & 31) * 128, n0 = (r >> 5) * 64;
  if (g == 0)       // Q pre-scaled by (1/8)*log2(e) so attention uses raw exp2
    gemm_phase<128, 64>(smem, qb_, wqb, bq, Qh, 0, 0.18033688011112f, m0, n0);
  else if (g == 1)
    gemm_phase<128, 64>(smem, kb_, wkb, bk, Kh, 0, 1.0f, m0, n0);
  else
    gemm_phase<128, 64>(smem, vb_, wvb, bv, VhT, 2, 1.0f, m0, n0);
}

// ---------------- Attention phase (r8 body): causal, S^T, no-max softmax -----
__device__ __forceinline__ void attn_phase(
    u16* smem, const u16* __restrict__ Qh, const u16* __restrict__ Kh,
    const u16* __restrict__ VhT, u16* __restrict__ Ctx, int bx) {
  u16* Kt = smem;          // 64*64 swizzled [s][dk]
  u16* Vt = smem + 4096;   // 64*64 swizzled [dk][s]
  u16* Ps = smem + 8192;   // 64*72 P[q_local][s], wave-private rows

  const int t = threadIdx.x;
  const int lane = t & 63, w = t >> 6;
  const int quad = lane >> 4, l16 = lane & 15;

  const int bh = bx & 31;
  const int i = bx >> 5;            // 0..31
  const int j = i >> 3, r0 = i & 7;
  const int u = (j == 0) ? 31 - r0 : (j == 1) ? r0 : (j == 2) ? 23 - r0 : 8 + r0;
  const int qb = u * 64;
  const int ntile = u + 1;

  const u16* Qp = Qh + (size_t)bh * S_ * DK_;
  const u16* Kp = Kh + (size_t)bh * S_ * DK_;
  const u16* Vp = VhT + (size_t)bh * DK_ * S_;

  bf16x8 bqf[2];
#pragma unroll
  for (int kk = 0; kk < 2; kk++)
    bqf[kk] = *reinterpret_cast<const bf16x8*>(
        &Qp[(size_t)(qb + w * 16 + l16) * DK_ + kk * 32 + quad * 8]);

  const u16 *gK[2], *gV[2]; u16 *lK[2], *lV[2];
#pragma unroll
  for (int i2 = 0; i2 < 2; i2++) {
    const int ch = (i2 * 4 + w) * 64 + lane;
    const int row = ch >> 3, c = ch & 7, cs = c ^ (row & 7);
    gK[i2] = Kp + (size_t)row * DK_ + cs * 8;
    gV[i2] = Vp + (size_t)row * S_ + cs * 8;
    lK[i2] = Kt + ((i2 * 4 + w) * 64) * 8;
    lV[i2] = Vt + ((i2 * 4 + w) * 64) * 8;
  }

  float l_run = 0.f;
  floatx4 o[4] = {};
  const int qg = qb + w * 16 + l16;

  for (int it = 0; it < ntile; it++) {
    const int j0 = it * 64;
#pragma unroll
    for (int i2 = 0; i2 < 2; i2++) {
      stage16(gK[i2] + (size_t)j0 * DK_, lK[i2]);
      stage16(gV[i2] + j0, lV[i2]);
    }
    __syncthreads();  // drain vmcnt: tile landed

    floatx4 sc[4] = {};
#pragma unroll
    for (int mt = 0; mt < 4; mt++) {
      const int row = mt * 16 + l16;
#pragma unroll
      for (int kk = 0; kk < 2; kk++) {
        const bf16x8 ak = *reinterpret_cast<const bf16x8*>(
            &Kt[(row * 8 + ((kk * 4 + quad) ^ (l16 & 7))) * 8]);
        sc[mt] = __builtin_amdgcn_mfma_f32_16x16x32_bf16(ak, bqf[kk], sc[mt], 0, 0, 0);
      }
    }

    const bool maskT = (it == ntile - 1);
    float psum = 0.f;
#pragma unroll
    for (int mt = 0; mt < 4; mt++) {
      float p[4];
#pragma unroll
      for (int r = 0; r < 4; r++) {
        float vsc = sc[mt][r];
        if (maskT && (j0 + mt * 16 + quad * 4 + r > qg)) vsc = -1e30f;
        p[r] = EXP2F(vsc);  // Q carries 0.125*log2e
        psum += p[r];
      }
      uint2 pu;  // truncation pack
      pu.x = (__float_as_uint(p[1]) & 0xffff0000u) | (__float_as_uint(p[0]) >> 16);
      pu.y = (__float_as_uint(p[3]) & 0xffff0000u) | (__float_as_uint(p[2]) >> 16);
      *reinterpret_cast<uint2*>(&Ps[(w * 16 + l16) * 72 + mt * 16 + quad * 4]) = pu;
    }
    psum += __shfl_xor(psum, 16);
    psum += __shfl_xor(psum, 32);
    l_run += psum;

#pragma unroll
    for (int kk = 0; kk < 2; kk++) {
      const bf16x8 ap = *reinterpret_cast<const bf16x8*>(
          &Ps[(w * 16 + l16) * 72 + kk * 32 + quad * 8]);
#pragma unroll
      for (int nt = 0; nt < 4; nt++) {
        const bf16x8 bv = *reinterpret_cast<const bf16x8*>(
            &Vt[((nt * 16 + l16) * 8 + ((kk * 4 + quad) ^ (l16 & 7))) * 8]);
        o[nt] = __builtin_amdgcn_mfma_f32_16x16x32_bf16(ap, bv, o[nt], 0, 0, 0);
      }
    }
    __syncthreads();  // waves done with Kt/Vt before next stage overwrites
  }

  const int bb = bh >> 4, hh = bh & 15;
#pragma unroll
  for (int r = 0; r < 4; r++) {
    const float lr = __shfl(l_run, quad * 4 + r);
    const float inv = 1.0f / lr;
    const int srow = qb + w * 16 + quad * 4 + r;
    u16* cp = Ctx + ((size_t)bb * S_ + srow) * D_ + hh * DK_;
#pragma unroll
    for (int nt = 0; nt < 4; nt++)
      cp[nt * 16 + l16] = f2bf(o[nt][r] * inv);
  }
}

// ---------------- Fused cooperative kernel ----------------
__global__ void __launch_bounds__(256, 4) fused_mha_kernel(
    const float* q, const float* k, const float* v,
    const float* Wq, const float* bq, const float* Wk, const float* bk,
    const float* Wv, const float* bv, const float* Wo, const float* bo,
    u16* ws, float* out) {
  __shared__ __align__(16) u16 smem[16384];  // 32 KB, reused by every phase
  const int bx = blockIdx.x;

  const size_t nW = (size_t)D_ * D_;
  const size_t nA = (size_t)M_ * D_;
  u16* wqb = ws;
  u16* wkb = wqb + nW;
  u16* wvb = wkb + nW;
  u16* wob = wvb + nW;
  u16* qb_ = wob + nW;
  u16* kb_ = qb_ + nA;
  u16* vb_ = kb_ + nA;
  u16* Qh  = vb_ + nA;
  u16* Kh  = Qh + nA;
  u16* VhT = Kh + nA;
  u16* Ctx = qb_;  // qb_ dead after QKV phase

  cvt_phase(bx, q, k, v, Wq, Wk, Wv, Wo, qb_, kb_, vb_, wqb, wkb, wvb, wob);
  __threadfence();
  cg::this_grid().sync();

  // P1: 1536 QKV jobs over 1024 block-slots
  qkv_job(smem, bx, qb_, kb_, vb_, wqb, wkb, wvb, bq, bk, bv, Qh, Kh, VhT);
  if (bx < 512)
    qkv_job(smem, 1024 + bx, qb_, kb_, vb_, wqb, wkb, wvb, bq, bk, bv, Qh, Kh, VhT);
  __threadfence();
  cg::this_grid().sync();

  attn_phase(smem, Qh, Kh, VhT, Ctx, bx);
  __threadfence();
  cg::this_grid().sync();

  // P3: output projection, 64x64 -> exactly 1024 jobs
  gemm_phase<64, 64>(smem, Ctx, wob, bo, out, 3, 1.0f,
                     (bx & 63) * 64, (bx >> 6) * 64);
}

// ---------------- Fallback kernels (same device functions, 4 launches) -------
__global__ __launch_bounds__(256) void cvt_fb(
    const float* q, const float* k, const float* v,
    const float* Wq, const float* Wk, const float* Wv, const float* Wo,
    u16* dq, u16* dk, u16* dv, u16* dwq, u16* dwk, u16* dwv, u16* dwo) {
  cvt_phase(blockIdx.x, q, k, v, Wq, Wk, Wv, Wo, dq, dk, dv, dwq, dwk, dwv, dwo);
}

__global__ __launch_bounds__(256) void qkv_fb(
    const u16* qa, const u16* ka, const u16* va,
    const u16* wq, const u16* wk, const u16* wv,
    const float* bq, const float* bk, const float* bv,
    u16* Qh, u16* Kh, u16* VhT) {
  __shared__ __align__(16) u16 smem[12288];
  // j = g*512 + n*32 + m  (x=m for XCD locality)
  const int j = blockIdx.z * 512 + blockIdx.y * 32 + blockIdx.x;
  qkv_job(smem, j, qa, ka, va, wq, wk, wv, bq, bk, bv, Qh, Kh, VhT);
}

__global__ __launch_bounds__(256) void attn_fb(
    const u16* Qh, const u16* Kh, const u16* VhT, u16* Ctx) {
  __shared__ __align__(16) u16 smem[12800];
  attn_phase(smem, Qh, Kh, VhT, Ctx, blockIdx.x);
}

__global__ __launch_bounds__(256) void o_fb(
    const u16* ctx, const u16* wo, const float* bo, float* out) {
  __shared__ __align__(16) u16 smem[8192];
  gemm_phase<64, 64>(smem, ctx, wo, bo, out, 3, 1.0f,
                     blockIdx.x * 64, blockIdx.y * 64);
}

extern "C" void kernel_launch(void* const* d_in, const int* in_sizes, int n_in,
                              void* d_out, int out_size, void* d_ws, size_t ws_size,
                              hipStream_t stream) {
  const float* q  = (const float*)d_in[0];
  const float* k  = (const float*)d_in[1];
  const float* v  = (const float*)d_in[2];
  // d_in[3]: causal tril mask, handled analytically
  const float* Wq = (const float*)d_in[4];
  const float* bq = (const float*)d_in[5];
  const float* Wk = (const float*)d_in[6];
  const float* bk = (const float*)d_in[7];
  const float* Wv = (const float*)d_in[8];
  const float* bv = (const float*)d_in[9];
  const float* Wo = (const float*)d_in[10];
  const float* bo = (const float*)d_in[11];
  u16* ws = (u16*)d_ws;
  float* out = (float*)d_out;

  void* args[] = {
      (void*)&q, (void*)&k, (void*)&v,
      (void*)&Wq, (void*)&bq, (void*)&Wk, (void*)&bk,
      (void*)&Wv, (void*)&bv, (void*)&Wo, (void*)&bo,
      (void*)&ws, (void*)&out};
  hipError_t err = hipLaunchCooperativeKernel((void*)fused_mha_kernel,
                                              dim3(1024), dim3(256),
                                              args, 0, stream);
  if (err != hipSuccess) {
    (void)hipGetLastError();  // clear sticky error, fall back to 4 launches
    const size_t nW = (size_t)D_ * D_;
    const size_t nA = (size_t)M_ * D_;
    u16* wqb = ws;
    u16* wkb = wqb + nW;
    u16* wvb = wkb + nW;
    u16* wob = wvb + nW;
    u16* qb_ = wob + nW;
    u16* kb_ = qb_ + nA;
    u16* vb_ = kb_ + nA;
    u16* Qh  = vb_ + nA;
    u16* Kh  = Qh + nA;
    u16* VhT = Kh + nA;
    u16* Ctx = qb_;

    cvt_fb<<<dim3(1024), 256, 0, stream>>>(q, k, v, Wq, Wk, Wv, Wo,
                                           qb_, kb_, vb_, wqb, wkb, wvb, wob);
    qkv_fb<<<dim3(32, 16, 3), 256, 0, stream>>>(
        qb_, kb_, vb_, wqb, wkb, wvb, bq, bk, bv, Qh, Kh, VhT);
    attn_fb<<<dim3(1024), 256, 0, stream>>>(Qh, Kh, VhT, Ctx);
    o_fb<<<dim3(64, 16), 256, 0, stream>>>(Ctx, wob, bo, out);
  }
}

// Round 11
// 234.234 us; speedup vs baseline: 4.0686x; 4.0686x over previous
//
#include <hip/hip_runtime.h>

#define B_ 2
#define S_ 2048
#define D_ 1024
#define H_ 16
#define DK_ 64
#define M_ 4096   // B_*S_

typedef unsigned short u16;
typedef __bf16 bf16x8 __attribute__((ext_vector_type(8)));
typedef float floatx4 __attribute__((ext_vector_type(4)));

#if __has_builtin(__builtin_amdgcn_exp2f)
#define EXP2F(x) __builtin_amdgcn_exp2f(x)
#else
#define EXP2F(x) exp2f(x)
#endif

__device__ __forceinline__ u16 f2bf(float f) {
  unsigned u = __float_as_uint(f);
  u += 0x7fffu + ((u >> 16) & 1u);  // RNE
  return (u16)(u >> 16);
}

// async global->LDS, 16B/lane; l is the wave-uniform base, data lands at l+lane*16
__device__ __forceinline__ void stage16(const void* g, void* l) {
  __builtin_amdgcn_global_load_lds(
      (const __attribute__((address_space(1))) unsigned int*)g,
      (__attribute__((address_space(3))) unsigned int*)l, 16, 0, 0);
}

// ---------------- fp32 -> bf16 conversion, all 7 tensors, one launch ----------
__global__ __launch_bounds__(256) void cvt_all_kernel(
    const float* __restrict__ q, const float* __restrict__ k, const float* __restrict__ v,
    const float* __restrict__ wq, const float* __restrict__ wk,
    const float* __restrict__ wv, const float* __restrict__ wo,
    u16* dq, u16* dk, u16* dv, u16* dwq, u16* dwk, u16* dwv, u16* dwo) {
  const float* s; u16* d; size_t base;
  const int bx = blockIdx.x;
  if (bx < 6144) {                 // q,k,v: 4M elems each, 2048 blocks each
    const int t0 = bx >> 11;
    base = (size_t)(bx & 2047) * 2048;
    s = t0 == 0 ? q : t0 == 1 ? k : v;
    d = t0 == 0 ? dq : t0 == 1 ? dk : dv;
  } else {                         // weights: 1M elems each, 512 blocks each
    const int t0 = (bx - 6144) >> 9;
    base = (size_t)((bx - 6144) & 511) * 2048;
    s = t0 == 0 ? wq : t0 == 1 ? wk : t0 == 2 ? wv : wo;
    d = t0 == 0 ? dwq : t0 == 1 ? dwk : t0 == 2 ? dwv : dwo;
  }
  const size_t i = base + (size_t)threadIdx.x * 8;
  const float4 f0 = *reinterpret_cast<const float4*>(s + i);
  const float4 f1 = *reinterpret_cast<const float4*>(s + i + 4);
  union { u16 h[8]; uint4 u; } cv;
  cv.h[0] = f2bf(f0.x); cv.h[1] = f2bf(f0.y); cv.h[2] = f2bf(f0.z); cv.h[3] = f2bf(f0.w);
  cv.h[4] = f2bf(f1.x); cv.h[5] = f2bf(f1.y); cv.h[6] = f2bf(f1.z); cv.h[7] = f2bf(f1.w);
  *reinterpret_cast<uint4*>(d + i) = cv.u;
}

// ---------------- GEMM: C = A @ W^T + bias, bf16 in, BK=32 dbuf -------------
// (frozen from r6/r8 — qkv/o not in top-5)
template <int BN>
__device__ __forceinline__ void gemm_body(
    const u16* __restrict__ A, const u16* __restrict__ W,
    const float* __restrict__ bias, void* __restrict__ outp,
    int mode, float scale) {
  constexpr int NT = BN / 32;
  constexpr int NBI = BN / 64;
  __shared__ __align__(16) u16 As[2][128 * 32];
  __shared__ __align__(16) u16 Bs[2][BN * 32];

  const int t = threadIdx.x;
  const int lane = t & 63, w = t >> 6;
  const int quad = lane >> 4, l16 = lane & 15;
  const int wm = w >> 1, wn = w & 1;
  const int m0 = blockIdx.x * 128, n0 = blockIdx.y * BN;

  const int sp = lane >> 3, ssw = lane & 7, sc = ssw ^ sp;  // staging unswizzle
  const u16 *gA[2], *gB[NBI]; u16 *lA[2], *lB[NBI];
#pragma unroll
  for (int i = 0; i < 2; i++) {
    const int ri = i * 4 + w;
    gA[i] = A + (size_t)(m0 + ri * 16 + 2 * sp + (sc >> 2)) * 1024 + (sc & 3) * 8;
    lA[i] = As[0] + ri * 64 * 8;
  }
#pragma unroll
  for (int i = 0; i < NBI; i++) {
    const int ri = i * 4 + w;
    gB[i] = W + (size_t)(n0 + ri * 16 + 2 * sp + (sc >> 2)) * 1024 + (sc & 3) * 8;
    lB[i] = Bs[0] + ri * 64 * 8;
  }

  floatx4 acc[4][NT] = {};

#pragma unroll
  for (int i = 0; i < 2; i++) stage16(gA[i], lA[i]);
#pragma unroll
  for (int i = 0; i < NBI; i++) stage16(gB[i], lB[i]);

  for (int k0 = 0; k0 < 1024; k0 += 32) {
    const int cur = (k0 >> 5) & 1, nxt = cur ^ 1;
    __syncthreads();
    if (k0 + 32 < 1024) {
#pragma unroll
      for (int i = 0; i < 2; i++) stage16(gA[i] + k0 + 32, lA[i] + nxt * 128 * 32);
#pragma unroll
      for (int i = 0; i < NBI; i++) stage16(gB[i] + k0 + 32, lB[i] + nxt * BN * 32);
    }
    bf16x8 af[4], bf[NT];
#pragma unroll
    for (int mt = 0; mt < 4; mt++) {
      const int row = wm * 64 + mt * 16 + l16;
      const int pg = row >> 1;
      const int sw = (((row & 1) << 2) | quad) ^ (pg & 7);
      af[mt] = *reinterpret_cast<const bf16x8*>(&As[cur][(pg * 8 + sw) * 8]);
    }
#pragma unroll
    for (int nt = 0; nt < NT; nt++) {
      const int row = wn * (NT * 16) + nt * 16 + l16;
      const int pg = row >> 1;
      const int sw = (((row & 1) << 2) | quad) ^ (pg & 7);
      bf[nt] = *reinterpret_cast<const bf16x8*>(&Bs[cur][(pg * 8 + sw) * 8]);
    }
#pragma unroll
    for (int mt = 0; mt < 4; mt++)
#pragma unroll
      for (int nt = 0; nt < NT; nt++)
        acc[mt][nt] = __builtin_amdgcn_mfma_f32_16x16x32_bf16(af[mt], bf[nt], acc[mt][nt], 0, 0, 0);
  }

#pragma unroll
  for (int mt = 0; mt < 4; mt++) {
    const int mbase = m0 + wm * 64 + mt * 16 + quad * 4;
    const int bb = mbase >> 11, s0v = mbase & 2047;
#pragma unroll
    for (int nt = 0; nt < NT; nt++) {
      const int n = n0 + wn * (NT * 16) + nt * 16 + l16;
      const float bvv = bias[n];
      if (mode == 0) {
        u16* Y = (u16*)outp;
        const int h = n >> 6, dk = n & 63;
#pragma unroll
        for (int r = 0; r < 4; r++)
          Y[(((size_t)(bb * H_ + h)) * S_ + (s0v + r)) * DK_ + dk] =
              f2bf((acc[mt][nt][r] + bvv) * scale);
      } else if (mode == 2) {
        u16* Y = (u16*)outp;
        const int h = n >> 6, dk = n & 63;
        union { u16 h4[4]; uint2 u; } pk2;
#pragma unroll
        for (int r = 0; r < 4; r++) pk2.h4[r] = f2bf(acc[mt][nt][r] + bvv);
        *reinterpret_cast<uint2*>(
            &Y[(((size_t)(bb * H_ + h)) * DK_ + dk) * S_ + s0v]) = pk2.u;
      } else {  // mode 3: fp32 [M,1024]
        float* Y = (float*)outp;
#pragma unroll
        for (int r = 0; r < 4; r++)
          Y[(size_t)(mbase + r) * 1024 + n] = acc[mt][nt][r] + bvv;
      }
    }
  }
}

__global__ __launch_bounds__(256) void qkv_gemm_kernel(
    const u16* qa, const u16* ka, const u16* va,
    const u16* wq, const u16* wk, const u16* wv,
    const float* bq, const float* bk, const float* bv,
    u16* Qh, u16* Kh, u16* VhT) {
  const int g = blockIdx.z;
  const u16* A = g == 0 ? qa : g == 1 ? ka : va;
  const u16* W = g == 0 ? wq : g == 1 ? wk : wv;
  const float* bias = g == 0 ? bq : g == 1 ? bk : bv;
  void* out = g == 0 ? (void*)Qh : g == 1 ? (void*)Kh : (void*)VhT;
  gemm_body<128>(A, W, bias, out, g == 2 ? 2 : 0,
                 g == 0 ? 0.18033688011112f : 1.0f);
}

__global__ __launch_bounds__(256) void o_gemm_kernel(
    const u16* ctx, const u16* wo, const float* bo, float* out) {
  gemm_body<64>(ctx, wo, bo, out, 3, 1.0f);
}

// ---------------- Flash attention, s-chunked (max chain = 16 tiles) ----------
// Theory (r8 counters): wall = longest per-block serial chain (u=31 -> 32
// tiles) + sparse tail (Occupancy 22%). Chunk the K-range at 16 tiles:
// u<16 -> 1 chunk, writes ctx directly; u>=16 -> 2 chunks writing bf16
// partial o + fp32 partial l (no-max softmax => combine is just o0+o1, l0+l1).
// 1536 blocks (6/CU), heavy chunks dispatched first (cidx sorted desc).
__global__ __launch_bounds__(256) void attn_kernel(
    const u16* __restrict__ Qh, const u16* __restrict__ Kh,
    const u16* __restrict__ VhT, u16* __restrict__ Ctx,
    u16* __restrict__ po, float* __restrict__ pl) {
  __shared__ __align__(16) u16 Kt[64 * 64];   // 8 KB swizzled [s][dk]
  __shared__ __align__(16) u16 Vt[64 * 64];   // 8 KB swizzled [dk][s]
  __shared__ __align__(16) u16 Ps[64 * 72];   // 9 KB P[q_local][s], wave-private rows

  const int t = threadIdx.x;
  const int lane = t & 63, w = t >> 6;
  const int quad = lane >> 4, l16 = lane & 15;

  const int bh = blockIdx.x & 31;
  const int cidx = blockIdx.x >> 5;  // 0..47, sorted desc by tile count
  int u, part;
  if (cidx < 17)       { u = 15 + cidx; part = 0; }       // 16 tiles
  else if (cidx == 17) { u = 31;        part = 1; }       // 16 tiles
  else {
    const int k2 = cidx - 18, tt = 15 - (k2 >> 1);        // tt tiles (15..1)
    if ((k2 & 1) == 0) { u = tt - 1;  part = 0; }
    else               { u = tt + 15; part = 1; }
  }
  const int qb = u * 64;
  const bool twopart = (u >= 16);
  const int tbeg = (part == 1) ? 16 : 0;
  const int tend = (twopart && part == 0) ? 16 : u + 1;

  const u16* Qp = Qh + (size_t)bh * S_ * DK_;
  const u16* Kp = Kh + (size_t)bh * S_ * DK_;
  const u16* Vp = VhT + (size_t)bh * DK_ * S_;

  // Q B-frags: B[k=dk][n=q], lane holds Q[q=l16][dk=quad*8+j+32kk]
  bf16x8 bqf[2];
#pragma unroll
  for (int kk = 0; kk < 2; kk++)
    bqf[kk] = *reinterpret_cast<const bf16x8*>(
        &Qp[(size_t)(qb + w * 16 + l16) * DK_ + kk * 32 + quad * 8]);

  const u16 *gK[2], *gV[2]; u16 *lK[2], *lV[2];
#pragma unroll
  for (int i2 = 0; i2 < 2; i2++) {
    const int ch = (i2 * 4 + w) * 64 + lane;
    const int row = ch >> 3, c = ch & 7, cs = c ^ (row & 7);
    gK[i2] = Kp + (size_t)row * DK_ + cs * 8;
    gV[i2] = Vp + (size_t)row * S_ + cs * 8;
    lK[i2] = Kt + ((i2 * 4 + w) * 64) * 8;
    lV[i2] = Vt + ((i2 * 4 + w) * 64) * 8;
  }

  float l_run = 0.f;
  floatx4 o[4] = {};
  const int qg = qb + w * 16 + l16;

  for (int it = tbeg; it < tend; it++) {
    const int j0 = it * 64;
#pragma unroll
    for (int i2 = 0; i2 < 2; i2++) {
      stage16(gK[i2] + (size_t)j0 * DK_, lK[i2]);
      stage16(gV[i2] + j0, lV[i2]);
    }
    __syncthreads();  // drain vmcnt: tile landed

    // S^T = K·Q^T
    floatx4 sc[4] = {};
#pragma unroll
    for (int mt = 0; mt < 4; mt++) {
      const int row = mt * 16 + l16;
#pragma unroll
      for (int kk = 0; kk < 2; kk++) {
        const bf16x8 ak = *reinterpret_cast<const bf16x8*>(
            &Kt[(row * 8 + ((kk * 4 + quad) ^ (l16 & 7))) * 8]);
        sc[mt] = __builtin_amdgcn_mfma_f32_16x16x32_bf16(ak, bqf[kk], sc[mt], 0, 0, 0);
      }
    }

    // no-max softmax (Q carries 0.125*log2e); diagonal tile is it == u
    const bool maskT = (it == u);
    float psum = 0.f;
#pragma unroll
    for (int mt = 0; mt < 4; mt++) {
      float p[4];
#pragma unroll
      for (int r = 0; r < 4; r++) {
        float vsc = sc[mt][r];
        if (maskT && (j0 + mt * 16 + quad * 4 + r > qg)) vsc = -1e30f;
        p[r] = EXP2F(vsc);
        psum += p[r];
      }
      uint2 pu;  // truncation pack
      pu.x = (__float_as_uint(p[1]) & 0xffff0000u) | (__float_as_uint(p[0]) >> 16);
      pu.y = (__float_as_uint(p[3]) & 0xffff0000u) | (__float_as_uint(p[2]) >> 16);
      *reinterpret_cast<uint2*>(&Ps[(w * 16 + l16) * 72 + mt * 16 + quad * 4]) = pu;
    }
    psum += __shfl_xor(psum, 16);
    psum += __shfl_xor(psum, 32);
    l_run += psum;

    // O += P·V^T (Ps rows wave-private: no barrier needed)
#pragma unroll
    for (int kk = 0; kk < 2; kk++) {
      const bf16x8 ap = *reinterpret_cast<const bf16x8*>(
          &Ps[(w * 16 + l16) * 72 + kk * 32 + quad * 8]);
#pragma unroll
      for (int nt = 0; nt < 4; nt++) {
        const bf16x8 bv = *reinterpret_cast<const bf16x8*>(
            &Vt[((nt * 16 + l16) * 8 + ((kk * 4 + quad) ^ (l16 & 7))) * 8]);
        o[nt] = __builtin_amdgcn_mfma_f32_16x16x32_bf16(ap, bv, o[nt], 0, 0, 0);
      }
    }
    __syncthreads();  // waves done with Kt/Vt before next stage overwrites
  }

  if (!twopart) {
    // ctx [b, s, h*64+dk] bf16, normalized
    const int bb = bh >> 4, hh = bh & 15;
#pragma unroll
    for (int r = 0; r < 4; r++) {
      const float lr = __shfl(l_run, quad * 4 + r);
      const float inv = 1.0f / lr;
      const int srow = qb + w * 16 + quad * 4 + r;
      u16* cp = Ctx + ((size_t)bb * S_ + srow) * D_ + hh * DK_;
#pragma unroll
      for (int nt = 0; nt < 4; nt++)
        cp[nt * 16 + l16] = f2bf(o[nt][r] * inv);
    }
  } else {
    // partial: po[part][bh][u-16][64][64] bf16 (unnormalized), pl fp32
    u16* pob = po + ((((size_t)part * 32 + bh) * 16 + (u - 16)) * 64) * 64;
#pragma unroll
    for (int r = 0; r < 4; r++) {
      const int row = w * 16 + quad * 4 + r;
#pragma unroll
      for (int nt = 0; nt < 4; nt++)
        pob[row * 64 + nt * 16 + l16] = f2bf(o[nt][r]);
    }
    if (quad == 0)
      pl[(((size_t)part * 32 + bh) * 16 + (u - 16)) * 64 + w * 16 + l16] = l_run;
  }
}

// ---------------- combine partials for q-rows >= 1024 of each (b,h) ----------
__global__ __launch_bounds__(256) void combine_kernel(
    const u16* __restrict__ po, const float* __restrict__ pl,
    u16* __restrict__ Ctx) {
  const int b = blockIdx.x;           // 512 = 32 bh x 16 u16
  const int bh = b & 31, ui = b >> 5;
  const int t = threadIdx.x;
  const int row = t >> 2, cg = (t & 3) * 16;
  const float l = pl[(((size_t)0 * 32 + bh) * 16 + ui) * 64 + row] +
                  pl[(((size_t)1 * 32 + bh) * 16 + ui) * 64 + row];
  const float inv = 1.0f / l;
  const u16* p0 = po + ((((size_t)0 * 32 + bh) * 16 + ui) * 64 + row) * 64 + cg;
  const u16* p1 = po + ((((size_t)1 * 32 + bh) * 16 + ui) * 64 + row) * 64 + cg;
  const int bb = bh >> 4, hh = bh & 15;
  const int s = (16 + ui) * 64 + row;
  u16* cp = Ctx + ((size_t)bb * S_ + s) * D_ + hh * DK_ + cg;
#pragma unroll
  for (int j2 = 0; j2 < 16; j2++) {
    const float v0 = __uint_as_float((unsigned)p0[j2] << 16);
    const float v1 = __uint_as_float((unsigned)p1[j2] << 16);
    cp[j2] = f2bf((v0 + v1) * inv);
  }
}

extern "C" void kernel_launch(void* const* d_in, const int* in_sizes, int n_in,
                              void* d_out, int out_size, void* d_ws, size_t ws_size,
                              hipStream_t stream) {
  const float* q  = (const float*)d_in[0];
  const float* k  = (const float*)d_in[1];
  const float* v  = (const float*)d_in[2];
  // d_in[3]: causal tril mask, handled analytically
  const float* Wq = (const float*)d_in[4];
  const float* bq = (const float*)d_in[5];
  const float* Wk = (const float*)d_in[6];
  const float* bk = (const float*)d_in[7];
  const float* Wv = (const float*)d_in[8];
  const float* bv = (const float*)d_in[9];
  const float* Wo = (const float*)d_in[10];
  const float* bo = (const float*)d_in[11];

  const size_t nW = (size_t)D_ * D_;
  const size_t nA = (size_t)M_ * D_;
  u16* wqb = (u16*)d_ws;
  u16* wkb = wqb + nW;
  u16* wvb = wkb + nW;
  u16* wob = wvb + nW;
  u16* qb_ = wob + nW;
  u16* kb_ = qb_ + nA;
  u16* vb_ = kb_ + nA;
  u16* Qh  = vb_ + nA;
  u16* Kh  = Qh + nA;
  u16* VhT = Kh + nA;
  u16* Ctx = qb_;                 // qb_ dead after QKV GEMM
  u16* po  = kb_;                 // kb_+vb_ (16 MB) dead after QKV: partial o
  float* pl = (float*)(VhT + nA); // +256 KB partial l

  cvt_all_kernel<<<dim3(8192), 256, 0, stream>>>(q, k, v, Wq, Wk, Wv, Wo,
                                                 qb_, kb_, vb_, wqb, wkb, wvb, wob);

  // grid.x = m-block (xcd = m%8 -> A-panel locality per XCD L2)
  qkv_gemm_kernel<<<dim3(M_ / 128, D_ / 128, 3), 256, 0, stream>>>(
      qb_, kb_, vb_, wqb, wkb, wvb, bq, bk, bv, Qh, Kh, VhT);

  attn_kernel<<<dim3(1536), 256, 0, stream>>>(Qh, Kh, VhT, Ctx, po, pl);

  combine_kernel<<<dim3(512), 256, 0, stream>>>(po, pl, Ctx);

  o_gemm_kernel<<<dim3(M_ / 128, D_ / 64), 256, 0, stream>>>(Ctx, wob, bo, (float*)d_out);
}